// Round 6
// baseline (217.200 us; speedup 1.0000x reference)
//
#include <hip/hip_runtime.h>

// RPN target generation for MI355X — G-split pair kernel + merge/finalize kernel.
// Outputs (float32, concat): [0,A) rpn_match; [A,5A) rpn_bbox (A x 4); [5A] num_positives.
//
// History: R3 LDS atomics/iter -> DS-queue stalls; R4 global atomics/iter ->
// memory-side meltdown (~110ns per contended atomic, calibrated); R5 per-block
// gkey merge = 261k atomics @ 1000-way contention on 256 addresses ~ 100us tail,
// plus grid-capped 4 waves/SIMD. R6: split G in 2 -> 2046 blocks (32 waves/CU,
// 100% occupancy), per-anchor partials via PLAIN stores to ws, per-gt winners
// via 32-way sharded atomicMax (contention /32, addresses x32).
//
// ws layout: [0, 2A*8)   akey   u64 {float best_bits : 32 | bg : 32} per (half, anchor)
//            [.., +2A*4) cmaxA  u32 crowd-max bits per (half, anchor)  (crowd inputs only)
//            [.., +G*32*8) gkeyS sharded per-gt argmax keys (pre-zeroed)
//            [.., +4) done u32, [+4] cnt i32 (pre-zeroed)

#define GMAX 256
#define SHARDS 32

// Faithful to the reference, including the intentional size "bug":
// gt_size = y2 + y1 (not y2 - y1); centre = 0.5 * (y1 + y2).
__device__ __forceinline__ float4 compute_deltas(float4 ab, float4 gb,
                                                 const float* __restrict__ sd) {
    float sy_g = gb.z + gb.x;   // box = (y1, x1, y2, x2) in (x,y,z,w)
    float sx_g = gb.w + gb.y;
    float sy_a = ab.z + ab.x;
    float sx_a = ab.w + ab.y;
    float4 d;
    d.x = (0.5f * (sy_g - sy_a) / sy_a) / sd[0];
    d.y = (0.5f * (sx_g - sx_a) / sx_a) / sd[1];
    d.z = logf(sy_g / sy_a) / sd[2];
    d.w = logf(sx_g / sx_a) / sd[3];
    return d;
}

__device__ __forceinline__ float iou_of(float4 ab, float a_area, float4 gb) {
    float y1 = fmaxf(ab.x, gb.x);
    float x1 = fmaxf(ab.y, gb.y);
    float y2 = fminf(ab.z, gb.z);
    float x2 = fminf(ab.w, gb.w);
    float inter = fmaxf(y2 - y1, 0.f) * fmaxf(x2 - x1, 0.f);
    float garea = (gb.z - gb.x) * (gb.w - gb.y);
    float uni = (a_area + garea) - inter;
    return inter * __builtin_amdgcn_rcpf(uni);   // exact 0 if inter==0
}

// ---------------- kernel 1: pair sweep over one G-half ----------------
__global__ __launch_bounds__(256) void rpn_pairs(
    const float4* __restrict__ anchors,       // [A]
    const int* __restrict__ valid,            // [A] jnp bool as int32
    const int* __restrict__ cls,              // [G]
    const float4* __restrict__ gt,            // [G]
    unsigned long long* __restrict__ akey,    // [2*A] per-(half,anchor) best
    unsigned* __restrict__ cmaxA,             // [2*A] crowd-max bits (crowd only)
    unsigned long long* __restrict__ gkeyS,   // [G*SHARDS], pre-zeroed
    int A, int G)
{
    __shared__ float4 s_gt[GMAX / 2 + 1];
    __shared__ float s_crowdf[GMAX / 2 + 1];
    __shared__ unsigned long long s_key[GMAX / 2 + 1];
    __shared__ int s_anycrowd;

    const int tid = threadIdx.x;
    const int bi = blockIdx.x;
    const int half = bi & 1;
    const int chunk = bi >> 1;
    const int Gh = (G + 1) >> 1;
    const int g0 = half * Gh;
    const int gn = min(G - g0, Gh);           // gts in this half (128 for G=256)

    if (tid == 0) s_anycrowd = 0;
    if (tid < G && cls[tid] < 0) s_anycrowd = 1;   // any_crowd over FULL G
    if (tid < gn) {
        s_gt[tid] = gt[g0 + tid];
        s_crowdf[tid] = (cls[g0 + tid] < 0) ? 1.0f : 0.0f;
        s_key[tid] = 0ULL;
    }
    __syncthreads();
    const int any_crowd = s_anycrowd;

    const int ai = chunk * 256 + tid;
    const bool in_range = (ai < A);
    float4 ab = in_range ? anchors[ai] : make_float4(0.f, 0.f, 1.f, 1.f);
    const bool v = in_range && (valid[ai] != 0);
    const float a_area = (ab.z - ab.x) * (ab.w - ab.y);

    float best;
    int bg = g0;
    float cm = 0.0f;
    unsigned long long m0 = 0ULL, m1 = 0ULL;

    if (!any_crowd && gn == 128) {
        // ---- fast path: no crowd, full half-slice; fully unrollable ----
        best = -1.0f;
        #pragma unroll
        for (int w = 0; w < 2; ++w) {
            unsigned long long mm = 0ULL;
            #pragma unroll 8
            for (int j = 0; j < 64; ++j) {
                int gg = (w << 6) + j;
                float4 gb = s_gt[gg];          // ds_read_b128, broadcast
                float y1 = fmaxf(ab.x, gb.x);
                float x1 = fmaxf(ab.y, gb.y);
                float y2 = fminf(ab.z, gb.z);
                float x2 = fminf(ab.w, gb.w);
                float inter = fmaxf(y2 - y1, 0.f) * fmaxf(x2 - x1, 0.f);
                float garea = (gb.z - gb.x) * (gb.w - gb.y);
                float uni = (a_area + garea) - inter;
                float iou = inter * __builtin_amdgcn_rcpf(uni);
                if (iou > best) { best = iou; bg = g0 + gg; }  // first-index tie-break
                if (iou > 0.0f) mm |= (1ULL << j);             // validity ANDed at drain
            }
            if (w == 0) m0 = mm; else m1 = mm;
        }
    } else {
        // ---- general path: crowd handling / odd sizes (correctness-only) ----
        best = -2.0f;
        for (int gg = 0; gg < gn; ++gg) {
            float4 gb = s_gt[gg];
            float iou = iou_of(ab, a_area, gb);
            float cf = s_crowdf[gg];
            float eff = (cf != 0.0f) ? -1.0f : iou;
            if (eff > best) { best = eff; bg = g0 + gg; }
            cm = fmaxf(cm, iou * cf);
            if (cf == 0.0f && iou > 0.0f) {
                if (gg < 64) m0 |= (1ULL << gg);
                else         m1 |= (1ULL << (gg - 64));
            }
        }
    }

    if (in_range) {
        akey[(size_t)half * A + ai] =
            (((unsigned long long)__float_as_uint(best)) << 32) | (unsigned)bg;
        if (any_crowd) cmaxA[(size_t)half * A + ai] = __float_as_uint(cm);
    }

    // ---- sparse drain (~5 bits/lane): rare LDS atomicMax into s_key ----
    if (v) {
        const unsigned lokey = ~(unsigned)ai;   // smaller ai -> larger lokey
        #pragma unroll
        for (int w = 0; w < 2; ++w) {
            unsigned long long m = (w == 0) ? m0 : m1;
            while (m != 0ULL) {
                int j = __builtin_ctzll(m);
                m &= (m - 1ULL);
                int gg = (w << 6) + j;
                float iou = iou_of(ab, a_area, s_gt[gg]);
                unsigned long long key =
                    (((unsigned long long)(__float_as_uint(iou) + 1u)) << 32) | lokey;
                atomicMax(&s_key[gg], key);
            }
        }
    }
    __syncthreads();

    // sharded global merge: contention ~ (A/256)/SHARDS ~ 32 per address
    if (tid < gn && s_key[tid] != 0ULL)
        atomicMax(&gkeyS[(size_t)(g0 + tid) * SHARDS + (chunk & (SHARDS - 1))],
                  s_key[tid]);
}

// ---------------- kernel 2: merge halves, write outputs, finalize ----------------
__global__ __launch_bounds__(256) void rpn_final(
    const float4* __restrict__ anchors,
    const int* __restrict__ valid,
    const int* __restrict__ cls,
    const float4* __restrict__ gt,
    const float* __restrict__ stdev,
    float* __restrict__ out,
    const unsigned long long* __restrict__ akey,
    const unsigned* __restrict__ cmaxA,
    unsigned long long* __restrict__ gkeyS,
    unsigned* __restrict__ done,
    int* __restrict__ cnt,
    int A, int G)
{
    __shared__ float4 s_gt[GMAX];
    __shared__ float s_crowdf[GMAX];
    __shared__ int s_anycrowd;
    __shared__ int s_cnt;
    __shared__ int s_islast;

    const int tid = threadIdx.x;
    if (tid == 0) { s_anycrowd = 0; s_cnt = 0; }
    if (tid < G) {
        s_gt[tid] = gt[tid];
        int c = cls[tid];
        s_crowdf[tid] = (c < 0) ? 1.0f : 0.0f;
        if (c < 0) s_anycrowd = 1;
    }
    __syncthreads();
    const int any_crowd = s_anycrowd;

    const int ai = blockIdx.x * 256 + tid;
    const bool in_range = (ai < A);
    bool posv = false;

    if (in_range) {
        unsigned long long k0 = akey[ai];
        unsigned long long k1 = akey[(size_t)A + ai];
        float b0 = __uint_as_float((unsigned)(k0 >> 32));
        float b1 = __uint_as_float((unsigned)(k1 >> 32));
        unsigned bg0 = (unsigned)k0, bg1 = (unsigned)k1;
        float best; int bg;
        if (b1 > b0 || (b1 == b0 && bg1 < bg0)) { best = b1; bg = (int)bg1; }
        else                                    { best = b0; bg = (int)bg0; }

        const bool v = (valid[ai] != 0);
        bool no_crowd = true;
        if (any_crowd) {
            float c0 = __uint_as_float(cmaxA[ai]);
            float c1 = __uint_as_float(cmaxA[(size_t)A + ai]);
            no_crowd = (fmaxf(c0, c1) < 0.001f);
        }
        bool pos = (best >= 0.7f);
        bool neg = (best < 0.3f) && no_crowd && !pos;
        posv = pos && v;

        out[ai] = v ? (pos ? 1.0f : (neg ? -1.0f : 0.0f)) : 0.0f;
        float4 d = make_float4(0.f, 0.f, 0.f, 0.f);
        if (posv) d = compute_deltas(anchors[ai], s_gt[bg], stdev);
        ((float4*)(out + A))[ai] = d;
    }

    unsigned long long pv = __ballot((int)posv);
    if ((tid & 63) == 0) atomicAdd(&s_cnt, (int)__popcll(pv));
    __syncthreads();
    if (tid == 0 && s_cnt > 0) atomicAdd(cnt, s_cnt);

    // ---- last-block-done: finalize (pos_from_gt scatter + count) ----
    __threadfence();
    if (tid == 0) {
        unsigned prev = atomicAdd(done, 1u);
        s_islast = (prev == gridDim.x - 1);
        s_cnt = 0;                             // reuse as flip counter
    }
    __syncthreads();
    if (!s_islast) return;
    __threadfence();

    if (tid < G && s_crowdf[tid] == 0.0f) {
        unsigned long long key = 0ULL;         // reduce the 32 shards
        for (int s = 0; s < SHARDS; ++s) {
            unsigned long long k = gkeyS[(size_t)tid * SHARDS + s];
            if (k > key) key = k;
        }
        int w;
        if (key != 0ULL) {
            w = (int)(~(unsigned)(key & 0xFFFFFFFFull));
        } else {
            // no valid anchor overlapped this gt: first valid anchor, else 0
            w = 0;
            for (int i = 0; i < A; ++i) { if (valid[i] != 0) { w = i; break; } }
        }
        if (valid[w] != 0) {
            float old = atomicExch(out + w, 1.0f);   // dedup gts sharing a winner
            if (old != 1.0f) {
                float4 ab2 = anchors[w];
                float a2 = (ab2.z - ab2.x) * (ab2.w - ab2.y);
                float b2 = -2.0f; int g2 = 0;
                for (int g = 0; g < G; ++g) {
                    float iou = iou_of(ab2, a2, s_gt[g]);
                    float eff = (s_crowdf[g] != 0.0f) ? -1.0f : iou;
                    if (eff > b2) { b2 = eff; g2 = g; }
                }
                ((float4*)(out + A))[w] = compute_deltas(ab2, s_gt[g2], stdev);
                atomicAdd(&s_cnt, 1);
            }
        }
    }
    __syncthreads();
    if (tid == 0) out[(size_t)5 * A] = (float)(*cnt + s_cnt);
}

// ---------------- fallback: R5 monolithic kernel (used if ws too small) --------
__global__ __launch_bounds__(256) void rpn_fused(
    const float4* __restrict__ anchors, const int* __restrict__ valid,
    const int* __restrict__ cls, const float4* __restrict__ gt,
    const float* __restrict__ stdev, float* __restrict__ out,
    unsigned long long* __restrict__ gkey, unsigned* __restrict__ done,
    int* __restrict__ cnt, int A, int G)
{
    __shared__ float4 s_gt[GMAX];
    __shared__ float s_crowdf[GMAX];
    __shared__ unsigned long long s_key[GMAX];
    __shared__ int s_anycrowd; __shared__ int s_cnt; __shared__ int s_islast;

    const int tid = threadIdx.x;
    if (tid == 0) { s_anycrowd = 0; s_cnt = 0; }
    if (tid < G) {
        s_gt[tid] = gt[tid];
        int c = cls[tid];
        s_crowdf[tid] = (c < 0) ? 1.0f : 0.0f;
        if (c < 0) s_anycrowd = 1;
        s_key[tid] = 0ULL;
    }
    __syncthreads();
    const int any_crowd = s_anycrowd;
    const int ai = blockIdx.x * 256 + tid;
    const bool in_range = (ai < A);
    float4 ab = in_range ? anchors[ai] : make_float4(0.f, 0.f, 1.f, 1.f);
    const bool v = in_range && (valid[ai] != 0);
    const float a_area = (ab.z - ab.x) * (ab.w - ab.y);
    const unsigned lokey = ~(unsigned)ai;

    float best = any_crowd ? -2.0f : -1.0f;
    int bg = 0; float crowd_max = 0.0f;
    unsigned long long ovmask[4];
    #pragma unroll
    for (int w = 0; w < 4; ++w) {
        unsigned long long m = 0ULL;
        #pragma unroll 4
        for (int j = 0; j < 64; ++j) {
            int g = (w << 6) + j;
            if (g >= G) break;
            float iou = iou_of(ab, a_area, s_gt[g]);
            float cf = s_crowdf[g];
            float eff = (any_crowd && cf != 0.0f) ? -1.0f : iou;
            if (eff > best) { best = eff; bg = g; }
            if (any_crowd) crowd_max = fmaxf(crowd_max, iou * cf);
            if (v && (cf == 0.0f) && iou > 0.0f) m |= (1ULL << j);
        }
        ovmask[w] = m;
    }
    #pragma unroll
    for (int w = 0; w < 4; ++w) {
        unsigned long long m = ovmask[w];
        while (m != 0ULL) {
            int j = __builtin_ctzll(m); m &= (m - 1ULL);
            int g = (w << 6) + j;
            float iou = iou_of(ab, a_area, s_gt[g]);
            unsigned long long key =
                (((unsigned long long)(__float_as_uint(iou) + 1u)) << 32) | lokey;
            atomicMax(&s_key[g], key);
        }
    }
    bool no_crowd = any_crowd ? (crowd_max < 0.001f) : true;
    bool pos = (best >= 0.7f);
    bool neg = (best < 0.3f) && no_crowd && !pos;
    unsigned long long pv = __ballot((int)(in_range && pos && v));
    if ((tid & 63) == 0) atomicAdd(&s_cnt, (int)__popcll(pv));
    if (in_range) {
        out[ai] = v ? (pos ? 1.0f : (neg ? -1.0f : 0.0f)) : 0.0f;
        float4 d = make_float4(0.f, 0.f, 0.f, 0.f);
        if (pos && v) d = compute_deltas(ab, s_gt[bg], stdev);
        ((float4*)(out + A))[ai] = d;
    }
    __syncthreads();
    if (tid < G && s_key[tid] != 0ULL) atomicMax(&gkey[tid], s_key[tid]);
    if (tid == 0 && s_cnt > 0) atomicAdd(cnt, s_cnt);
    __threadfence();
    if (tid == 0) {
        unsigned prev = atomicAdd(done, 1u);
        s_islast = (prev == gridDim.x - 1);
        s_cnt = 0;
    }
    __syncthreads();
    if (!s_islast) return;
    __threadfence();
    if (tid < G && s_crowdf[tid] == 0.0f) {
        unsigned long long key = gkey[tid];
        int w;
        if (key != 0ULL) w = (int)(~(unsigned)(key & 0xFFFFFFFFull));
        else { w = 0; for (int i = 0; i < A; ++i) { if (valid[i] != 0) { w = i; break; } } }
        if (valid[w] != 0) {
            float old = atomicExch(out + w, 1.0f);
            if (old != 1.0f) {
                float4 ab2 = anchors[w];
                float a2 = (ab2.z - ab2.x) * (ab2.w - ab2.y);
                float b2 = -2.0f; int g2 = 0;
                for (int g = 0; g < G; ++g) {
                    float iou = iou_of(ab2, a2, s_gt[g]);
                    float eff = (s_crowdf[g] != 0.0f) ? -1.0f : iou;
                    if (eff > b2) { b2 = eff; g2 = g; }
                }
                ((float4*)(out + A))[w] = compute_deltas(ab2, s_gt[g2], stdev);
                atomicAdd(&s_cnt, 1);
            }
        }
    }
    __syncthreads();
    if (tid == 0) out[(size_t)5 * A] = (float)(*cnt + s_cnt);
}

extern "C" void kernel_launch(void* const* d_in, const int* in_sizes, int n_in,
                              void* d_out, int out_size, void* d_ws, size_t ws_size,
                              hipStream_t stream) {
    const float4* anchors = (const float4*)d_in[0];
    const int* valid      = (const int*)d_in[1];   // jnp bool -> int32 per element
    const int* cls        = (const int*)d_in[2];
    const float4* gt      = (const float4*)d_in[3];
    const float* stdev    = (const float*)d_in[4];
    float* out            = (float*)d_out;

    const int A = in_sizes[0] / 4;
    const int G = in_sizes[2];                 // 256
    const int blocks = (A + 255) / 256;        // 1023

    const size_t akey_bytes  = (size_t)2 * A * 8;
    const size_t cmax_bytes  = (size_t)2 * A * 4;
    const size_t shard_bytes = (size_t)G * SHARDS * 8;
    const size_t needed = akey_bytes + cmax_bytes + shard_bytes + 16;

    if (ws_size >= needed && G <= GMAX) {
        unsigned long long* akey = (unsigned long long*)d_ws;
        unsigned* cmaxA = (unsigned*)((char*)d_ws + akey_bytes);
        unsigned long long* gkeyS =
            (unsigned long long*)((char*)d_ws + akey_bytes + cmax_bytes);
        unsigned* done = (unsigned*)((char*)gkeyS + shard_bytes);
        int* cnt       = (int*)((char*)gkeyS + shard_bytes + 4);

        hipMemsetAsync((void*)gkeyS, 0, shard_bytes + 8, stream);
        rpn_pairs<<<2 * blocks, 256, 0, stream>>>(anchors, valid, cls, gt,
                                                  akey, cmaxA, gkeyS, A, G);
        rpn_final<<<blocks, 256, 0, stream>>>(anchors, valid, cls, gt, stdev, out,
                                              akey, cmaxA, gkeyS, done, cnt, A, G);
    } else {
        unsigned long long* gkey = (unsigned long long*)d_ws;
        unsigned* done = (unsigned*)((char*)d_ws + 2048);
        int* cnt       = (int*)((char*)d_ws + 2052);
        hipMemsetAsync(d_ws, 0, 2056, stream);
        rpn_fused<<<blocks, 256, 0, stream>>>(anchors, valid, cls, gt, stdev, out,
                                              gkey, done, cnt, A, G);
    }
}

// Round 7
// 143.100 us; speedup vs baseline: 1.5178x; 1.5178x over previous
//
#include <hip/hip_runtime.h>

// RPN target generation for MI355X — 3-kernel pipeline, no contended atomics.
// Outputs (float32, concat): [0,A) rpn_match; [A,5A) rpn_bbox (A x 4); [5A] num_positives.
//
// Atomic history (calibrated): memory-side same-address atomic ~100ns/op.
//  R4: 1.4M global atomicMax on 256 addrs -> 800us. R5: 261k on 256 addrs +
//  1023 on `done` -> 100us tail. R6: rpn_final 100us @ VALUBusy 0.66% = the
//  1023-deep `done` storm. R7: NO O(grid) same-address atomics anywhere —
//  per-block partials via plain stores; finalize is a separate 1-block kernel.
//
// ws layout: [0, 2A*8)    akey   u64 {best_bits:32 | bg:32} per (half, anchor)
//            [.., +2A*4)  cmaxA  u32 crowd-max bits (crowd inputs only)
//            [.., +G*32*8) gkeyS sharded per-gt argmax keys (memset 0)
//            [.., +nb1*4) pcount i32 per-merge-block positive count (plain stores)

#define GMAX 256
#define SHARDS 32

// Faithful to the reference, including the intentional size "bug":
// gt_size = y2 + y1 (not y2 - y1); centre = 0.5 * (y1 + y2).
__device__ __forceinline__ float4 compute_deltas(float4 ab, float4 gb,
                                                 const float* __restrict__ sd) {
    float sy_g = gb.z + gb.x;   // box = (y1, x1, y2, x2) in (x,y,z,w)
    float sx_g = gb.w + gb.y;
    float sy_a = ab.z + ab.x;
    float sx_a = ab.w + ab.y;
    float4 d;
    d.x = (0.5f * (sy_g - sy_a) / sy_a) / sd[0];
    d.y = (0.5f * (sx_g - sx_a) / sx_a) / sd[1];
    d.z = logf(sy_g / sy_a) / sd[2];
    d.w = logf(sx_g / sx_a) / sd[3];
    return d;
}

__device__ __forceinline__ float iou_of(float4 ab, float a_area, float4 gb) {
    float y1 = fmaxf(ab.x, gb.x);
    float x1 = fmaxf(ab.y, gb.y);
    float y2 = fminf(ab.z, gb.z);
    float x2 = fminf(ab.w, gb.w);
    float inter = fmaxf(y2 - y1, 0.f) * fmaxf(x2 - x1, 0.f);
    float garea = (gb.z - gb.x) * (gb.w - gb.y);
    float uni = (a_area + garea) - inter;
    return inter * __builtin_amdgcn_rcpf(uni);   // exact 0 if inter==0
}

// ---------- kernel 1: pair sweep, 2 anchors/thread, one G-half/block ----------
__global__ __launch_bounds__(256) void rpn_pairs2(
    const float4* __restrict__ anchors,       // [A]
    const int* __restrict__ valid,            // [A] jnp bool as int32
    const int* __restrict__ cls,              // [G]
    const float4* __restrict__ gt,            // [G]
    unsigned long long* __restrict__ akey,    // [2*A]
    unsigned* __restrict__ cmaxA,             // [2*A] (crowd only)
    unsigned long long* __restrict__ gkeyS,   // [G*SHARDS], pre-zeroed
    int A, int G)
{
    __shared__ float4 s_gt[GMAX / 2];
    __shared__ float s_crowdf[GMAX / 2];
    __shared__ unsigned long long s_key[GMAX / 2];
    __shared__ int s_anycrowd;

    const int tid = threadIdx.x;
    const int bi = blockIdx.x;
    const int half = bi & 1;
    const int chunk = bi >> 1;
    const int Gh = (G + 1) >> 1;
    const int g0 = half * Gh;
    const int gn = min(G - g0, Gh);           // 128 for G=256

    if (tid == 0) s_anycrowd = 0;
    if (tid < G && cls[tid] < 0) s_anycrowd = 1;   // any_crowd over FULL G
    if (tid < gn) {
        s_gt[tid] = gt[g0 + tid];
        s_crowdf[tid] = (cls[g0 + tid] < 0) ? 1.0f : 0.0f;
        s_key[tid] = 0ULL;
    }
    __syncthreads();
    const int any_crowd = s_anycrowd;

    const int ai0 = chunk * 512 + tid;
    const int ai1 = ai0 + 256;
    const bool ir0 = (ai0 < A), ir1 = (ai1 < A);
    float4 a0 = ir0 ? anchors[ai0] : make_float4(0.f, 0.f, 1.f, 1.f);
    float4 a1 = ir1 ? anchors[ai1] : make_float4(0.f, 0.f, 1.f, 1.f);
    const bool v0 = ir0 && (valid[ai0] != 0);
    const bool v1 = ir1 && (valid[ai1] != 0);
    const float ar0 = (a0.z - a0.x) * (a0.w - a0.y);
    const float ar1 = (a1.z - a1.x) * (a1.w - a1.y);

    float b0v, b1v;
    int bg0 = g0, bg1 = g0;
    float cm0 = 0.0f, cm1 = 0.0f;
    unsigned long long m00 = 0ULL, m01 = 0ULL, m10 = 0ULL, m11 = 0ULL;

    if (!any_crowd && gn == 128) {
        b0v = -1.0f; b1v = -1.0f;
        #pragma unroll
        for (int w = 0; w < 2; ++w) {
            unsigned long long ma = 0ULL, mb = 0ULL;
            #pragma unroll 4
            for (int j = 0; j < 64; ++j) {
                int gg = (w << 6) + j;
                float4 gb = s_gt[gg];          // one ds_read_b128 feeds 2 anchors
                float garea = (gb.z - gb.x) * (gb.w - gb.y);
                // anchor 0
                {
                    float y1 = fmaxf(a0.x, gb.x), x1 = fmaxf(a0.y, gb.y);
                    float y2 = fminf(a0.z, gb.z), x2 = fminf(a0.w, gb.w);
                    float inter = fmaxf(y2 - y1, 0.f) * fmaxf(x2 - x1, 0.f);
                    float iou = inter * __builtin_amdgcn_rcpf((ar0 + garea) - inter);
                    if (iou > b0v) { b0v = iou; bg0 = g0 + gg; }
                    if (iou > 0.0f) ma |= (1ULL << j);
                }
                // anchor 1
                {
                    float y1 = fmaxf(a1.x, gb.x), x1 = fmaxf(a1.y, gb.y);
                    float y2 = fminf(a1.z, gb.z), x2 = fminf(a1.w, gb.w);
                    float inter = fmaxf(y2 - y1, 0.f) * fmaxf(x2 - x1, 0.f);
                    float iou = inter * __builtin_amdgcn_rcpf((ar1 + garea) - inter);
                    if (iou > b1v) { b1v = iou; bg1 = g0 + gg; }
                    if (iou > 0.0f) mb |= (1ULL << j);
                }
            }
            if (w == 0) { m00 = ma; m10 = mb; } else { m01 = ma; m11 = mb; }
        }
    } else {
        // general path: crowd handling / odd sizes (correctness-only)
        b0v = -2.0f; b1v = -2.0f;
        for (int gg = 0; gg < gn; ++gg) {
            float4 gb = s_gt[gg];
            float cf = s_crowdf[gg];
            float i0 = iou_of(a0, ar0, gb);
            float i1 = iou_of(a1, ar1, gb);
            float e0 = (cf != 0.0f) ? -1.0f : i0;
            float e1 = (cf != 0.0f) ? -1.0f : i1;
            if (e0 > b0v) { b0v = e0; bg0 = g0 + gg; }
            if (e1 > b1v) { b1v = e1; bg1 = g0 + gg; }
            cm0 = fmaxf(cm0, i0 * cf);
            cm1 = fmaxf(cm1, i1 * cf);
            if (cf == 0.0f) {
                if (i0 > 0.0f) { if (gg < 64) m00 |= (1ULL << gg); else m01 |= (1ULL << (gg - 64)); }
                if (i1 > 0.0f) { if (gg < 64) m10 |= (1ULL << gg); else m11 |= (1ULL << (gg - 64)); }
            }
        }
    }

    if (ir0) {
        akey[(size_t)half * A + ai0] =
            (((unsigned long long)__float_as_uint(b0v)) << 32) | (unsigned)bg0;
        if (any_crowd) cmaxA[(size_t)half * A + ai0] = __float_as_uint(cm0);
    }
    if (ir1) {
        akey[(size_t)half * A + ai1] =
            (((unsigned long long)__float_as_uint(b1v)) << 32) | (unsigned)bg1;
        if (any_crowd) cmaxA[(size_t)half * A + ai1] = __float_as_uint(cm1);
    }

    // ---- sparse drain (~2-3 bits/lane/anchor): rare LDS atomicMax ----
    if (v0) {
        const unsigned lokey = ~(unsigned)ai0;
        #pragma unroll
        for (int w = 0; w < 2; ++w) {
            unsigned long long m = (w == 0) ? m00 : m01;
            while (m != 0ULL) {
                int j = __builtin_ctzll(m); m &= (m - 1ULL);
                int gg = (w << 6) + j;
                float iou = iou_of(a0, ar0, s_gt[gg]);
                atomicMax(&s_key[gg],
                    (((unsigned long long)(__float_as_uint(iou) + 1u)) << 32) | lokey);
            }
        }
    }
    if (v1) {
        const unsigned lokey = ~(unsigned)ai1;
        #pragma unroll
        for (int w = 0; w < 2; ++w) {
            unsigned long long m = (w == 0) ? m10 : m11;
            while (m != 0ULL) {
                int j = __builtin_ctzll(m); m &= (m - 1ULL);
                int gg = (w << 6) + j;
                float iou = iou_of(a1, ar1, s_gt[gg]);
                atomicMax(&s_key[gg],
                    (((unsigned long long)(__float_as_uint(iou) + 1u)) << 32) | lokey);
            }
        }
    }
    __syncthreads();

    // sharded global merge: ~16-way contention spread over G*SHARDS addresses
    if (tid < gn && s_key[tid] != 0ULL)
        atomicMax(&gkeyS[(size_t)(g0 + tid) * SHARDS + (chunk & (SHARDS - 1))],
                  s_key[tid]);
}

// ---------- kernel 2: merge halves, write match/bbox, plain-store counts ----------
__global__ __launch_bounds__(256) void rpn_merge(
    const float4* __restrict__ anchors,
    const int* __restrict__ valid,
    const int* __restrict__ cls,
    const float4* __restrict__ gt,
    const float* __restrict__ stdev,
    float* __restrict__ out,
    const unsigned long long* __restrict__ akey,
    const unsigned* __restrict__ cmaxA,
    int* __restrict__ pcount,                  // [gridDim.x], plain stores
    int A, int G)
{
    __shared__ float4 s_gt[GMAX];
    __shared__ int s_anycrowd;
    __shared__ int s_cnt;

    const int tid = threadIdx.x;
    if (tid == 0) { s_anycrowd = 0; s_cnt = 0; }
    if (tid < G) {
        s_gt[tid] = gt[tid];
        if (cls[tid] < 0) s_anycrowd = 1;
    }
    __syncthreads();
    const int any_crowd = s_anycrowd;

    const int ai = blockIdx.x * 256 + tid;
    bool posv = false;
    if (ai < A) {
        unsigned long long k0 = akey[ai];
        unsigned long long k1 = akey[(size_t)A + ai];
        float bb0 = __uint_as_float((unsigned)(k0 >> 32));
        float bb1 = __uint_as_float((unsigned)(k1 >> 32));
        unsigned g_0 = (unsigned)k0, g_1 = (unsigned)k1;
        float best; int bg;
        if (bb1 > bb0 || (bb1 == bb0 && g_1 < g_0)) { best = bb1; bg = (int)g_1; }
        else                                        { best = bb0; bg = (int)g_0; }

        const bool v = (valid[ai] != 0);
        bool no_crowd = true;
        if (any_crowd)
            no_crowd = (fmaxf(__uint_as_float(cmaxA[ai]),
                              __uint_as_float(cmaxA[(size_t)A + ai])) < 0.001f);
        bool pos = (best >= 0.7f);
        bool neg = (best < 0.3f) && no_crowd && !pos;
        posv = pos && v;

        out[ai] = v ? (pos ? 1.0f : (neg ? -1.0f : 0.0f)) : 0.0f;
        float4 d = make_float4(0.f, 0.f, 0.f, 0.f);
        if (posv) d = compute_deltas(anchors[ai], s_gt[bg], stdev);
        ((float4*)(out + A))[ai] = d;
    }

    unsigned long long pv = __ballot((int)posv);
    if ((tid & 63) == 0) atomicAdd(&s_cnt, (int)__popcll(pv));   // LDS, 4 ops
    __syncthreads();
    if (tid == 0) pcount[blockIdx.x] = s_cnt;                    // PLAIN store
}

// ---------- kernel 3: single-block finalize (pos_from_gt + count) ----------
__global__ __launch_bounds__(256) void rpn_finalize(
    const float4* __restrict__ anchors,
    const int* __restrict__ valid,
    const int* __restrict__ cls,
    const float4* __restrict__ gt,
    const float* __restrict__ stdev,
    float* __restrict__ out,
    const unsigned long long* __restrict__ gkeyS,
    const int* __restrict__ pcount,
    int nb1, int A, int G)
{
    __shared__ float4 s_gt[GMAX];
    __shared__ float s_crowdf[GMAX];
    __shared__ int s_tot[256];
    __shared__ int s_cnt;

    const int tid = threadIdx.x;
    if (tid == 0) s_cnt = 0;
    if (tid < G) {
        s_gt[tid] = gt[tid];
        s_crowdf[tid] = (cls[tid] < 0) ? 1.0f : 0.0f;
    }
    int acc = 0;
    for (int i = tid; i < nb1; i += 256) acc += pcount[i];
    s_tot[tid] = acc;
    __syncthreads();
    for (int s = 128; s > 0; s >>= 1) {
        if (tid < s) s_tot[tid] += s_tot[tid + s];
        __syncthreads();
    }

    if (tid < G && s_crowdf[tid] == 0.0f) {
        unsigned long long key = 0ULL;
        for (int s = 0; s < SHARDS; ++s) {
            unsigned long long k = gkeyS[(size_t)tid * SHARDS + s];
            if (k > key) key = k;
        }
        int w;
        if (key != 0ULL) {
            w = (int)(~(unsigned)(key & 0xFFFFFFFFull));
        } else {
            // no valid anchor overlapped this gt: first valid anchor, else 0
            w = 0;
            for (int i = 0; i < A; ++i) { if (valid[i] != 0) { w = i; break; } }
        }
        if (valid[w] != 0) {
            float old = atomicExch(out + w, 1.0f);   // <=256 ops, mostly distinct
            if (old != 1.0f) {
                float4 ab2 = anchors[w];
                float a2 = (ab2.z - ab2.x) * (ab2.w - ab2.y);
                float b2 = -2.0f; int g2 = 0;
                for (int g = 0; g < G; ++g) {
                    float iou = iou_of(ab2, a2, s_gt[g]);
                    float eff = (s_crowdf[g] != 0.0f) ? -1.0f : iou;
                    if (eff > b2) { b2 = eff; g2 = g; }
                }
                ((float4*)(out + A))[w] = compute_deltas(ab2, s_gt[g2], stdev);
                atomicAdd(&s_cnt, 1);
            }
        }
    }
    __syncthreads();
    if (tid == 0) out[(size_t)5 * A] = (float)(s_tot[0] + s_cnt);
}

// ---------------- fallback: monolithic kernel (used only if ws too small) ------
__global__ __launch_bounds__(256) void rpn_fused(
    const float4* __restrict__ anchors, const int* __restrict__ valid,
    const int* __restrict__ cls, const float4* __restrict__ gt,
    const float* __restrict__ stdev, float* __restrict__ out,
    unsigned long long* __restrict__ gkey, unsigned* __restrict__ done,
    int* __restrict__ cnt, int A, int G)
{
    __shared__ float4 s_gt[GMAX];
    __shared__ float s_crowdf[GMAX];
    __shared__ unsigned long long s_key[GMAX];
    __shared__ int s_anycrowd; __shared__ int s_cnt; __shared__ int s_islast;

    const int tid = threadIdx.x;
    if (tid == 0) { s_anycrowd = 0; s_cnt = 0; }
    if (tid < G) {
        s_gt[tid] = gt[tid];
        int c = cls[tid];
        s_crowdf[tid] = (c < 0) ? 1.0f : 0.0f;
        if (c < 0) s_anycrowd = 1;
        s_key[tid] = 0ULL;
    }
    __syncthreads();
    const int any_crowd = s_anycrowd;
    const int ai = blockIdx.x * 256 + tid;
    const bool in_range = (ai < A);
    float4 ab = in_range ? anchors[ai] : make_float4(0.f, 0.f, 1.f, 1.f);
    const bool v = in_range && (valid[ai] != 0);
    const float a_area = (ab.z - ab.x) * (ab.w - ab.y);
    const unsigned lokey = ~(unsigned)ai;

    float best = any_crowd ? -2.0f : -1.0f;
    int bg = 0; float crowd_max = 0.0f;
    unsigned long long ovmask[4];
    #pragma unroll
    for (int w = 0; w < 4; ++w) {
        unsigned long long m = 0ULL;
        #pragma unroll 4
        for (int j = 0; j < 64; ++j) {
            int g = (w << 6) + j;
            if (g >= G) break;
            float iou = iou_of(ab, a_area, s_gt[g]);
            float cf = s_crowdf[g];
            float eff = (any_crowd && cf != 0.0f) ? -1.0f : iou;
            if (eff > best) { best = eff; bg = g; }
            if (any_crowd) crowd_max = fmaxf(crowd_max, iou * cf);
            if (v && (cf == 0.0f) && iou > 0.0f) m |= (1ULL << j);
        }
        ovmask[w] = m;
    }
    #pragma unroll
    for (int w = 0; w < 4; ++w) {
        unsigned long long m = ovmask[w];
        while (m != 0ULL) {
            int j = __builtin_ctzll(m); m &= (m - 1ULL);
            int g = (w << 6) + j;
            float iou = iou_of(ab, a_area, s_gt[g]);
            atomicMax(&s_key[g],
                (((unsigned long long)(__float_as_uint(iou) + 1u)) << 32) | lokey);
        }
    }
    bool no_crowd = any_crowd ? (crowd_max < 0.001f) : true;
    bool pos = (best >= 0.7f);
    bool neg = (best < 0.3f) && no_crowd && !pos;
    unsigned long long pv = __ballot((int)(in_range && pos && v));
    if ((tid & 63) == 0) atomicAdd(&s_cnt, (int)__popcll(pv));
    if (in_range) {
        out[ai] = v ? (pos ? 1.0f : (neg ? -1.0f : 0.0f)) : 0.0f;
        float4 d = make_float4(0.f, 0.f, 0.f, 0.f);
        if (pos && v) d = compute_deltas(ab, s_gt[bg], stdev);
        ((float4*)(out + A))[ai] = d;
    }
    __syncthreads();
    if (tid < G && s_key[tid] != 0ULL) atomicMax(&gkey[tid], s_key[tid]);
    if (tid == 0 && s_cnt > 0) atomicAdd(cnt, s_cnt);
    __threadfence();
    if (tid == 0) {
        unsigned prev = atomicAdd(done, 1u);
        s_islast = (prev == gridDim.x - 1);
        s_cnt = 0;
    }
    __syncthreads();
    if (!s_islast) return;
    __threadfence();
    if (tid < G && s_crowdf[tid] == 0.0f) {
        unsigned long long key = gkey[tid];
        int w;
        if (key != 0ULL) w = (int)(~(unsigned)(key & 0xFFFFFFFFull));
        else { w = 0; for (int i = 0; i < A; ++i) { if (valid[i] != 0) { w = i; break; } } }
        if (valid[w] != 0) {
            float old = atomicExch(out + w, 1.0f);
            if (old != 1.0f) {
                float4 ab2 = anchors[w];
                float a2 = (ab2.z - ab2.x) * (ab2.w - ab2.y);
                float b2 = -2.0f; int g2 = 0;
                for (int g = 0; g < G; ++g) {
                    float iou = iou_of(ab2, a2, s_gt[g]);
                    float eff = (s_crowdf[g] != 0.0f) ? -1.0f : iou;
                    if (eff > b2) { b2 = eff; g2 = g; }
                }
                ((float4*)(out + A))[w] = compute_deltas(ab2, s_gt[g2], stdev);
                atomicAdd(&s_cnt, 1);
            }
        }
    }
    __syncthreads();
    if (tid == 0) out[(size_t)5 * A] = (float)(*cnt + s_cnt);
}

extern "C" void kernel_launch(void* const* d_in, const int* in_sizes, int n_in,
                              void* d_out, int out_size, void* d_ws, size_t ws_size,
                              hipStream_t stream) {
    const float4* anchors = (const float4*)d_in[0];
    const int* valid      = (const int*)d_in[1];   // jnp bool -> int32 per element
    const int* cls        = (const int*)d_in[2];
    const float4* gt      = (const float4*)d_in[3];
    const float* stdev    = (const float*)d_in[4];
    float* out            = (float*)d_out;

    const int A = in_sizes[0] / 4;
    const int G = in_sizes[2];                     // 256
    const int nb1 = (A + 255) / 256;               // 1023 merge blocks
    const int chunks = (A + 511) / 512;            // 512
    const int nbp = 2 * chunks;                    // 1024 pair blocks

    const size_t akey_bytes  = (size_t)2 * A * 8;
    const size_t cmax_bytes  = (size_t)2 * A * 4;
    const size_t shard_bytes = (size_t)G * SHARDS * 8;
    const size_t pcnt_bytes  = (size_t)nb1 * 4;
    const size_t needed = akey_bytes + cmax_bytes + shard_bytes + pcnt_bytes + 16;

    if (ws_size >= needed && G <= GMAX) {
        unsigned long long* akey = (unsigned long long*)d_ws;
        unsigned* cmaxA = (unsigned*)((char*)d_ws + akey_bytes);
        unsigned long long* gkeyS =
            (unsigned long long*)((char*)d_ws + akey_bytes + cmax_bytes);
        int* pcount = (int*)((char*)gkeyS + shard_bytes);

        hipMemsetAsync((void*)gkeyS, 0, shard_bytes, stream);
        rpn_pairs2<<<nbp, 256, 0, stream>>>(anchors, valid, cls, gt,
                                            akey, cmaxA, gkeyS, A, G);
        rpn_merge<<<nb1, 256, 0, stream>>>(anchors, valid, cls, gt, stdev, out,
                                           akey, cmaxA, pcount, A, G);
        rpn_finalize<<<1, 256, 0, stream>>>(anchors, valid, cls, gt, stdev, out,
                                            gkeyS, pcount, nb1, A, G);
    } else {
        unsigned long long* gkey = (unsigned long long*)d_ws;
        unsigned* done = (unsigned*)((char*)d_ws + 2048);
        int* cnt       = (int*)((char*)d_ws + 2052);
        hipMemsetAsync(d_ws, 0, 2056, stream);
        rpn_fused<<<nb1, 256, 0, stream>>>(anchors, valid, cls, gt, stdev, out,
                                           gkey, done, cnt, A, G);
    }
}